// Round 2
// baseline (439.464 us; speedup 1.0000x reference)
//
#include <hip/hip_runtime.h>
#include <hip/hip_fp16.h>

typedef _Float16 h2 __attribute__((ext_vector_type(2)));

#define LOG2E 1.4426950408889634f
#define LN2   0.6931471805599453f

__device__ __forceinline__ float fast_exp2(float x) {
#if __has_builtin(__builtin_amdgcn_exp2f)
    return __builtin_amdgcn_exp2f(x);
#else
    return exp2f(x);
#endif
}

__device__ __forceinline__ float dot2(h2 a, h2 b, float c) {
#if __has_builtin(__builtin_amdgcn_fdot2)
    return __builtin_amdgcn_fdot2(a, b, c, false);
#else
    return (float)a.x * (float)b.x + (float)a.y * (float)b.y + c;
#endif
}

__device__ __forceinline__ h2 pack_h2(float a, float b) {
#if __has_builtin(__builtin_amdgcn_cvt_pkrtz)
    return __builtin_bit_cast(h2, __builtin_amdgcn_cvt_pkrtz(a, b));
#else
    h2 t; t.x = (_Float16)a; t.y = (_Float16)b; return t;
#endif
}

// One block per batch element b. Thread j owns state-column j.
// Linear exp-space recursion: v_new(j) = [sum_i u_i * E(i,j)] * 2^(cm2_j + log2e*emit_t(j))
// with u = v * 2^-k (k = exponent of v[0], tracked in running offset C).
__launch_bounds__(256, 1)
__global__ void crf_main(const float* __restrict__ emissions,
                         const int*   __restrict__ tags,
                         const float* __restrict__ mask,
                         const float* __restrict__ trans,
                         float*       __restrict__ ws) {
    const int T = 512, N = 256;
    const int b = blockIdx.x;
    const int j = threadIdx.x;

    __shared__ alignas(16) _Float16 u_lds[256];
    __shared__ float v0_sh;
    __shared__ float red[256];

    // ---- load transition column j into registers as fp16 pairs (E in VGPRs) ----
    const float* tcol = trans + j;            // column j: stride N, coalesced across lanes
    float cmax = -1e30f;
    #pragma unroll 8
    for (int i = 0; i < N; ++i) cmax = fmaxf(cmax, tcol[i * N]);
    const float cm2 = cmax * LOG2E;           // log2-domain column max

    h2 Er[128];                               // E(2k,j), E(2k+1,j) packed; E = 2^(t*log2e - cm2) in (0,1]
    #pragma unroll
    for (int k = 0; k < 128; ++k) {
        float ea = fast_exp2(tcol[(2 * k)     * N] * LOG2E - cm2);
        float eb = fast_exp2(tcol[(2 * k + 1) * N] * LOG2E - cm2);
        Er[k] = pack_h2(ea, eb);
    }

    // ---- init: v = 2^(log2e * emit[b,0,j]), running exponent offset C = 0 ----
    const float* em_base = emissions + ((size_t)b * T) * N + j;
    float v = fast_exp2(em_base[0] * LOG2E);
    float C = 0.f;
    float em_next = em_base[N];               // emit for t=1, prefetched

    for (int t = 1; t < T; ++t) {
        float em = em_next;
        if (t + 1 < T) em_next = em_base[(size_t)(t + 1) * N];   // prefetch next step

        // broadcast v[0]; renormalize by its exact power-of-two exponent
        if (j == 0) v0_sh = v;
        __syncthreads();                                          // bar A
        float v0 = v0_sh;
        int   k  = (__float_as_int(v0) >> 23) - 127;              // ilogb(v0), v0 > 0 always
        float r  = __int_as_float((127 - k) << 23);               // exact 2^-k
        C += (float)k;
        u_lds[j] = (_Float16)(v * r);
        __syncthreads();                                          // bar B

        // matvec: acc = sum_i u_i * E(i,j); u broadcast from LDS, E from VGPRs
        float a0 = 0.f, a1 = 0.f, a2 = 0.f, a3 = 0.f;
        const uint4* ub = (const uint4*)u_lds;
        #pragma unroll
        for (int i = 0; i < 32; ++i) {
            uint4 u4 = ub[i];                                     // 8 fp16 of u, broadcast read
            a0 = dot2(__builtin_bit_cast(h2, u4.x), Er[4 * i + 0], a0);
            a1 = dot2(__builtin_bit_cast(h2, u4.y), Er[4 * i + 1], a1);
            a2 = dot2(__builtin_bit_cast(h2, u4.z), Er[4 * i + 2], a2);
            a3 = dot2(__builtin_bit_cast(h2, u4.w), Er[4 * i + 3], a3);
        }
        float acc = (a0 + a1) + (a2 + a3);
        v = acc * fast_exp2(fmaf(em, LOG2E, cm2));                // fold emit + colmax back in
    }

    // ---- Z_b = ln2 * (C + log2(sum_j v_j)) ----
    red[j] = v;
    __syncthreads();
    #pragma unroll
    for (int s = 128; s > 0; s >>= 1) {
        if (j < s) red[j] += red[j + s];
        __syncthreads();
    }
    float Z = (C + log2f(red[0])) * LN2;
    __syncthreads();   // everyone done reading red[0] before reuse

    // ---- gold score (gather) ----
    float gp = 0.f;
    const int*   tg  = tags + (size_t)b * T;
    const float* mk  = mask + (size_t)b * T;
    const float* emb = emissions + ((size_t)b * T) * N;
    for (int t = 1 + j; t < T; t += 256) {
        int tt = tg[t], tp = tg[t - 1];
        gp += (emb[(size_t)t * N + tt] + trans[(size_t)tp * N + tt]) * mk[t];
    }
    if (j == 0) gp += emb[tg[0]];
    red[j] = gp;
    __syncthreads();
    #pragma unroll
    for (int s = 128; s > 0; s >>= 1) {
        if (j < s) red[j] += red[j + s];
        __syncthreads();
    }
    if (j == 0) ws[b] = Z - red[0];
}

// Deterministic mean over the 128 per-batch results.
__global__ void crf_finalize(const float* __restrict__ ws, float* __restrict__ out) {
    int l = threadIdx.x;                 // 64 threads, one wave
    float s = ws[l] + ws[l + 64];
    #pragma unroll
    for (int d = 32; d > 0; d >>= 1) s += __shfl_down(s, d);
    if (l == 0) out[0] = s * (1.0f / 128.0f);
}

extern "C" void kernel_launch(void* const* d_in, const int* in_sizes, int n_in,
                              void* d_out, int out_size, void* d_ws, size_t ws_size,
                              hipStream_t stream) {
    const float* emissions = (const float*)d_in[0];
    const int*   tags      = (const int*)  d_in[1];
    const float* mask      = (const float*)d_in[2];
    const float* trans     = (const float*)d_in[3];
    float* out = (float*)d_out;
    float* ws  = (float*)d_ws;           // 128 floats of scratch

    crf_main<<<dim3(128), dim3(256), 0, stream>>>(emissions, tags, mask, trans, ws);
    crf_finalize<<<dim3(1), dim3(64), 0, stream>>>(ws, out);
}